// Round 2
// baseline (739.531 us; speedup 1.0000x reference)
//
#include <hip/hip_runtime.h>
#include <hip/hip_bf16.h>
#include <math.h>

#define NROWS 8192
#define INDIM 768
#define TD    72
#define DM    24
#define MKEYS 8192
#define KSEL  32
#define HN    256
#define K3CAND 128

#define TWO_PI_F 6.283185307179586f

__device__ __forceinline__ float gelu_exact(float v){
  return 0.5f * v * (1.0f + erff(v * 0.7071067811865476f));
}

// async global->LDS (gfx950): LDS dest = uniform base + lane*size, global src per-lane
__device__ __forceinline__ void gl_lds16(const float* g, float* l) {
  __builtin_amdgcn_global_load_lds((const __attribute__((address_space(1))) unsigned int*)g,
                                   (__attribute__((address_space(3))) unsigned int*)l, 16, 0, 0);
}
__device__ __forceinline__ void gl_lds4(const float* g, float* l) {
  __builtin_amdgcn_global_load_lds((const __attribute__((address_space(1))) unsigned int*)g,
                                   (__attribute__((address_space(3))) unsigned int*)l, 4, 0, 0);
}

// ---------------------------------------------------------------------------
// K1: y = x@W_in.T + b_in ; LN(72); GELU; ricci einsum + mean over 3 -> q(24)
// ---------------------------------------------------------------------------
__global__ __launch_bounds__(256) void k1_encode(
    const float* __restrict__ x, const float* __restrict__ Wi,
    const float* __restrict__ bi, const float* __restrict__ gi,
    const float* __restrict__ bbi, const float* __restrict__ ricci,
    float* __restrict__ qvec, float* __restrict__ qnorm)
{
  __shared__ float xs[16][132];
  __shared__ float Ws[TD][132];
  __shared__ float zs[16][73];
  __shared__ float zb[16][25];
  const int t = threadIdx.x;
  const int r2 = t >> 4, ks = (t >> 3) & 1, u = t & 7;
  const int row0 = blockIdx.x * 16;

  float acc[9];
#pragma unroll
  for (int j = 0; j < 9; j++) acc[j] = 0.f;

  for (int kc = 0; kc < 6; kc++) {
    __syncthreads();
#pragma unroll
    for (int i = 0; i < 2; i++) {
      int idx = t + 256 * i;
      int rr = idx >> 5, kk = (idx & 31) << 2;
      *(float4*)&xs[rr][kk] = *(const float4*)&x[(size_t)(row0 + rr) * INDIM + kc * 128 + kk];
    }
#pragma unroll
    for (int i = 0; i < 9; i++) {
      int idx = t + 256 * i;
      int rr = idx >> 5, kk = (idx & 31) << 2;
      *(float4*)&Ws[rr][kk] = *(const float4*)&Wi[(size_t)rr * INDIM + kc * 128 + kk];
    }
    __syncthreads();
    const int kb = ks * 64;
#pragma unroll 4
    for (int kq = 0; kq < 16; kq++) {
      const float4 xv = *(const float4*)&xs[r2][kb + kq * 4];
#pragma unroll
      for (int j = 0; j < 9; j++) {
        const float4 wv = *(const float4*)&Ws[u + 8 * j][kb + kq * 4];
        acc[j] = fmaf(xv.x, wv.x, fmaf(xv.y, wv.y, fmaf(xv.z, wv.z, fmaf(xv.w, wv.w, acc[j]))));
      }
    }
  }
#pragma unroll
  for (int j = 0; j < 9; j++) acc[j] += __shfl_xor(acc[j], 8);

  float yv[9];
  float ps = 0.f, pq = 0.f;
#pragma unroll
  for (int j = 0; j < 9; j++) {
    const int o = u + 8 * j;
    yv[j] = acc[j] + bi[o];
    ps += yv[j]; pq += yv[j] * yv[j];
  }
#pragma unroll
  for (int m = 1; m < 8; m <<= 1) { ps += __shfl_xor(ps, m); pq += __shfl_xor(pq, m); }
  const float mean = ps * (1.f / 72.f);
  const float var  = pq * (1.f / 72.f) - mean * mean;
  const float rstd = rsqrtf(var + 1e-5f);
#pragma unroll
  for (int j = 0; j < 9; j++) {
    const int o = u + 8 * j;
    const float z = gelu_exact((yv[j] - mean) * rstd * gi[o] + bbi[o]);
    if (ks == 0) zs[r2][o] = z;
  }
  __syncthreads();
  {
    const int kt = t & 15;
    for (int e = kt; e < 24; e += 16)
      zb[r2][e] = (zs[r2][3 * e] + zs[r2][3 * e + 1] + zs[r2][3 * e + 2]) * (1.f / 3.f);
  }
  __syncthreads();
  {
    const int kt = t & 15;
    float qnp = 0.f;
    for (int d = kt; d < 24; d += 16) {
      float qd = 0.f;
#pragma unroll
      for (int e = 0; e < 24; e++) qd = fmaf(zb[r2][e], ricci[e * 24 + d], qd);
      qvec[(size_t)(row0 + r2) * DM + d] = qd;
      qnp = fmaf(qd, qd, qnp);
    }
#pragma unroll
    for (int m = 1; m < 16; m <<= 1) qnp += __shfl_xor(qnp, m, 16);
    if (kt == 0) qnorm[row0 + r2] = qnp;
  }
}

// ---------------------------------------------------------------------------
// K2: key norms + quantum-phase means
// ---------------------------------------------------------------------------
__global__ __launch_bounds__(256) void k2_prep(
    const float* __restrict__ keys, const float* __restrict__ qp,
    float* __restrict__ kn, float* __restrict__ pm)
{
  const int m = blockIdx.x * 256 + threadIdx.x;
  float s = 0.f;
#pragma unroll
  for (int d = 0; d < DM; d++) { const float v = keys[(size_t)m * DM + d]; s = fmaf(v, v, s); }
  kn[m] = s;
  float p = 0.f;
#pragma unroll
  for (int q = 0; q < 8; q++) p += tanhf(qp[(size_t)m * 8 + q]);
  pm[m] = p * 0.125f;
}

// ---------------------------------------------------------------------------
// K3 v2: distances + exact top-32 + softmax + gain.
// 256 thr / 32 rows per block (8 rows per wave), grid 256 (1 block/CU).
// Keys staged key-major in LDS via async global_load_lds (double-buffered,
// counted vmcnt). Reads: 6x ds_read_b128 per key, q for 8 rows in VGPRs.
// Two-pass group-min (groups of 128 keys) -> threshold -> compaction ->
// exact rank-select. Same arithmetic chain as round-1 (bit-identical d2).
// ---------------------------------------------------------------------------
__global__ __launch_bounds__(256, 2) void k3_topk(
    const float* __restrict__ qvec, const float* __restrict__ qnorm,
    const float* __restrict__ keys, const float* __restrict__ kn,
    const float* __restrict__ fw,  const float* __restrict__ pm,
    float* __restrict__ w_out, int* __restrict__ itop_out, float* __restrict__ gain_out)
{
  __shared__ __align__(16) float ks[2][256 * 24];   // 48 KB, key-major, linear
  __shared__ float knch[2][256];                    // 2 KB
  __shared__ float qsm[32][24];
  __shared__ float qnsm[32];
  __shared__ float gmins[64][33];                   // [group][row]
  __shared__ float Ts[32];
  __shared__ unsigned flg[2][32];                   // [word][row] live-group bits
  __shared__ unsigned candV[32][K3CAND];
  __shared__ int      candI[32][K3CAND];
  __shared__ int cnt[32];
  __shared__ float wV[32][KSEL];
  __shared__ int   wI[32][KSEL];

  const int t = threadIdx.x;
  const int wv = t >> 6, lane = t & 63;
  const int row0 = blockIdx.x * 32;
  const int wv8 = wv * 8;

#define K3_STAGE(c_, b_) do {                                                  \
    const float* gk_ = keys + (size_t)(c_) * 256 * 24;                         \
    _Pragma("unroll")                                                          \
    for (int i_ = 0; i_ < 6; i_++) {                                           \
      const int offf_ = (wv * 6 + i_) * 256;  /* floats */                     \
      gl_lds16(gk_ + offf_ + lane * 4, &ks[b_][offf_]);                        \
    }                                                                          \
    _Pragma("unroll")                                                          \
    for (int i_ = 0; i_ < 4; i_++) {                                           \
      gl_lds4(kn + (size_t)(c_) * 256 + i_ * 64 + lane, &knch[b_][i_ * 64]);   \
    }                                                                          \
  } while (0)

  // one-time: q rows to LDS then regs; init cnt/flg
  for (int idx = t; idx < 32 * DM; idx += 256) qsm[idx / DM][idx % DM] = qvec[(size_t)row0 * DM + idx];
  if (t < 32) { qnsm[t] = qnorm[row0 + t]; cnt[t] = 0; }
  if (t < 64) ((unsigned*)flg)[t] = 0;
  K3_STAGE(0, 0);
  __syncthreads();

  float q[8][24];
  float qn[8];
#pragma unroll
  for (int r = 0; r < 8; r++) {
    qn[r] = qnsm[wv8 + r];
#pragma unroll
    for (int d = 0; d < DM; d++) q[r][d] = qsm[wv8 + r][d];
  }

  // ---------------- pass A: group minima ----------------
  for (int c = 0; c < 32; c++) {
    const int buf = c & 1;
    if (c < 31) {
      K3_STAGE(c + 1, buf ^ 1);
      asm volatile("s_waitcnt vmcnt(10)" ::: "memory");
    } else {
      asm volatile("s_waitcnt vmcnt(0)" ::: "memory");
    }
    __syncthreads();
    const float* kb = &ks[buf][0];
    const float* knb = &knch[buf][0];
    float mcur[8];
#pragma unroll
    for (int il = 0; il < 4; il++) {
      const int kk = lane + 64 * il;
      float kv[24];
      {
        const float4 a0 = *(const float4*)&kb[kk * 24 + 0];
        const float4 a1 = *(const float4*)&kb[kk * 24 + 4];
        const float4 a2 = *(const float4*)&kb[kk * 24 + 8];
        const float4 a3 = *(const float4*)&kb[kk * 24 + 12];
        const float4 a4 = *(const float4*)&kb[kk * 24 + 16];
        const float4 a5 = *(const float4*)&kb[kk * 24 + 20];
        kv[0]=a0.x; kv[1]=a0.y; kv[2]=a0.z; kv[3]=a0.w;
        kv[4]=a1.x; kv[5]=a1.y; kv[6]=a1.z; kv[7]=a1.w;
        kv[8]=a2.x; kv[9]=a2.y; kv[10]=a2.z; kv[11]=a2.w;
        kv[12]=a3.x; kv[13]=a3.y; kv[14]=a3.z; kv[15]=a3.w;
        kv[16]=a4.x; kv[17]=a4.y; kv[18]=a4.z; kv[19]=a4.w;
        kv[20]=a5.x; kv[21]=a5.y; kv[22]=a5.z; kv[23]=a5.w;
      }
      const float knn = knb[kk];
#pragma unroll
      for (int r = 0; r < 8; r++) {
        float dot = 0.f;
#pragma unroll
        for (int d = 0; d < DM; d++) dot = fmaf(kv[d], q[r][d], dot);
        const float d2 = fmaf(-2.f, dot, qn[r] + knn);
        if ((il & 1) == 0) mcur[r] = d2;
        else               mcur[r] = fminf(mcur[r], d2);
      }
      if (il & 1) {
        const int g = 2 * c + (il >> 1);
#pragma unroll
        for (int r = 0; r < 8; r++) {
          float gm = mcur[r];
#pragma unroll
          for (int m = 1; m < 64; m <<= 1) gm = fminf(gm, __shfl_xor(gm, m));
          if (lane == 0) gmins[g][wv8 + r] = gm;
        }
      }
    }
    __syncthreads();
  }

  // overlap: start staging chunk 0 for pass B while doing threshold work
  K3_STAGE(0, 0);

  // ---------------- threshold: 32nd smallest group-min per row ----------------
  float vloc[8];
  {
    const int r = t & 31, i = t >> 5;       // i in 0..7, each handles 8 groups
#pragma unroll
    for (int u = 0; u < 8; u++) vloc[u] = gmins[i * 8 + u][r];
    int rk[8], eq[8];
#pragma unroll
    for (int u = 0; u < 8; u++) { rk[u] = 0; eq[u] = 0; }
    for (int g = 0; g < 64; g++) {
      const float gv = gmins[g][r];
#pragma unroll
      for (int u = 0; u < 8; u++) { rk[u] += (gv < vloc[u]); eq[u] += (gv == vloc[u]); }
    }
#pragma unroll
    for (int u = 0; u < 8; u++)
      if (rk[u] <= 31 && rk[u] + eq[u] > 31) Ts[r] = vloc[u];
  }
  __syncthreads();
  {
    const int r = t & 31, i = t >> 5;
    const float T = Ts[r];
    const float Tm = T + fabsf(T) * 1e-6f + 1e-20f;
    unsigned bits = 0;
#pragma unroll
    for (int u = 0; u < 8; u++) bits |= (vloc[u] <= Tm) ? (1u << u) : 0u;
    atomicOr(&flg[i >> 2][r], bits << ((i & 3) * 8));
  }
  __syncthreads();

  float TmA[8];
#pragma unroll
  for (int r = 0; r < 8; r++) {
    const float T = Ts[wv8 + r];
    TmA[r] = T + fabsf(T) * 1e-6f + 1e-20f;
  }

  // ---------------- pass B: recompute live groups, compact candidates ----------------
  for (int c = 0; c < 32; c++) {
    const int buf = c & 1;
    if (c < 31) {
      K3_STAGE(c + 1, buf ^ 1);
      asm volatile("s_waitcnt vmcnt(10)" ::: "memory");
    } else {
      asm volatile("s_waitcnt vmcnt(0)" ::: "memory");
    }
    __syncthreads();
    const float* kb = &ks[buf][0];
    const float* knb = &knch[buf][0];
    const int wc = c >> 4;
    unsigned fm[8];
#pragma unroll
    for (int r = 0; r < 8; r++) fm[r] = flg[wc][wv8 + r];
    unsigned anym = 0;
#pragma unroll
    for (int r = 0; r < 8; r++) anym |= fm[r];
#pragma unroll
    for (int il = 0; il < 4; il++) {
      const int g = 2 * c + (il >> 1);
      const unsigned gb = 1u << (g & 31);
      if (!(anym & gb)) continue;          // wave-uniform skip
      const int kk = lane + 64 * il;
      float kv[24];
      {
        const float4 a0 = *(const float4*)&kb[kk * 24 + 0];
        const float4 a1 = *(const float4*)&kb[kk * 24 + 4];
        const float4 a2 = *(const float4*)&kb[kk * 24 + 8];
        const float4 a3 = *(const float4*)&kb[kk * 24 + 12];
        const float4 a4 = *(const float4*)&kb[kk * 24 + 16];
        const float4 a5 = *(const float4*)&kb[kk * 24 + 20];
        kv[0]=a0.x; kv[1]=a0.y; kv[2]=a0.z; kv[3]=a0.w;
        kv[4]=a1.x; kv[5]=a1.y; kv[6]=a1.z; kv[7]=a1.w;
        kv[8]=a2.x; kv[9]=a2.y; kv[10]=a2.z; kv[11]=a2.w;
        kv[12]=a3.x; kv[13]=a3.y; kv[14]=a3.z; kv[15]=a3.w;
        kv[16]=a4.x; kv[17]=a4.y; kv[18]=a4.z; kv[19]=a4.w;
        kv[20]=a5.x; kv[21]=a5.y; kv[22]=a5.z; kv[23]=a5.w;
      }
      const float knn = knb[kk];
#pragma unroll
      for (int r = 0; r < 8; r++) {
        if (fm[r] & gb) {                  // wave-uniform per row
          float dot = 0.f;
#pragma unroll
          for (int d = 0; d < DM; d++) dot = fmaf(kv[d], q[r][d], dot);
          const float d2 = fmaf(-2.f, dot, qn[r] + knn);
          if (d2 <= TmA[r]) {
            const int pos = atomicAdd(&cnt[wv8 + r], 1);
            if (pos < K3CAND) {
              candV[wv8 + r][pos] = __float_as_uint(fmaxf(d2, 0.f));
              candI[wv8 + r][pos] = c * 256 + kk;
            }
          }
        }
      }
    }
    __syncthreads();
  }

  for (int idx = t; idx < 32 * KSEL; idx += 256) { wV[idx >> 5][idx & 31] = 1e30f; wI[idx >> 5][idx & 31] = 0; }
  __syncthreads();

  // ---------------- exact rank-select top-32 ----------------
  {
    const int r = t >> 3, kt = t & 7;      // 32 rows x 8 threads
    const int C = min(cnt[r], K3CAND);
    for (int ci = kt; ci < C; ci += 8) {
      const unsigned v = candV[r][ci];
      const unsigned key = (unsigned)candI[r][ci];
      int rk = 0;
      for (int j = 0; j < C; j++) {
        const unsigned vj = candV[r][j];
        rk += (vj < v) || (vj == v && (unsigned)candI[r][j] < key);
      }
      if (rk < KSEL) { wV[r][rk] = __uint_as_float(v); wI[r][rk] = (int)key; }
    }
  }
  __syncthreads();

  // ---------------- softmax over -dist, gain ----------------
  float sc;
  {
    const float f0 = fw[0], f1 = fw[1], f2 = fw[2], f3 = fw[3];
    const float mx = fmaxf(fmaxf(f0, f1), fmaxf(f2, f3));
    const float e0 = expf(f0 - mx), e1 = expf(f1 - mx), e2 = expf(f2 - mx), e3 = expf(f3 - mx);
    sc = (e0 + 0.5f * e1 + 0.25f * e2 + 0.125f * e3) / (e0 + e1 + e2 + e3);
  }
  {
    const int r = t >> 3, kt = t & 7;
    const float dA = sqrtf(wV[r][kt]) * sc;
    const float dB = sqrtf(wV[r][kt + 8]) * sc;
    const float dC = sqrtf(wV[r][kt + 16]) * sc;
    const float dD = sqrtf(wV[r][kt + 24]) * sc;
    float mn = fminf(fminf(dA, dB), fminf(dC, dD));
#pragma unroll
    for (int m = 1; m < 8; m <<= 1) mn = fminf(mn, __shfl_xor(mn, m, 8));
    const float eA = expf(mn - dA), eB = expf(mn - dB), eC = expf(mn - dC), eD = expf(mn - dD);
    float s = eA + eB + eC + eD;
#pragma unroll
    for (int m = 1; m < 8; m <<= 1) s += __shfl_xor(s, m, 8);
    const float w0 = eA / s, w1 = eB / s, w2 = eC / s, w3 = eD / s;
    const int k0 = wI[r][kt], k1 = wI[r][kt + 8], k2 = wI[r][kt + 16], k3 = wI[r][kt + 24];
    float gp = w0 * pm[k0] + w1 * pm[k1] + w2 * pm[k2] + w3 * pm[k3];
#pragma unroll
    for (int m = 1; m < 8; m <<= 1) gp += __shfl_xor(gp, m, 8);
    const size_t row = (size_t)(row0 + r);
    w_out[row * KSEL + kt] = w0;       w_out[row * KSEL + kt + 8] = w1;
    w_out[row * KSEL + kt + 16] = w2;  w_out[row * KSEL + kt + 24] = w3;
    itop_out[row * KSEL + kt] = k0;    itop_out[row * KSEL + kt + 8] = k1;
    itop_out[row * KSEL + kt + 16] = k2; itop_out[row * KSEL + kt + 24] = k3;
    if (kt == 0) gain_out[row] = 1.f + 0.02f * gp;
  }
#undef K3_STAGE
}

// ---------------------------------------------------------------------------
// K4: p = x@key_phase_W.T + b ; Kf = FFT(e^{i 2pi sigmoid(p)}) * e^{i ek}
// ---------------------------------------------------------------------------
__global__ __launch_bounds__(256) void k4_phase(
    const float* __restrict__ x, const float* __restrict__ Wp,
    const float* __restrict__ bp, const float* __restrict__ ek,
    float* __restrict__ kf_re, float* __restrict__ kf_im)
{
  __shared__ float xs[16][36];
  __shared__ float Ws[HN][36];
  __shared__ float sre[16][260];
  __shared__ float sim_[16][260];
  __shared__ float twc[HN], tws[HN];
  const int t = threadIdx.x;
  const int row0 = blockIdx.x * 16;
  {
    const float a = (float)t * (TWO_PI_F / 256.f);
    twc[t] = cosf(a); tws[t] = sinf(a);
  }
  const int r = t >> 4, cg = t & 15;
  float acc[16];
#pragma unroll
  for (int j = 0; j < 16; j++) acc[j] = bp[cg + 16 * j];

  for (int kc = 0; kc < 24; kc++) {
    __syncthreads();
    if (t < 128) {
      const int rr = t >> 3, kk = (t & 7) << 2;
      *(float4*)&xs[rr][kk] = *(const float4*)&x[(size_t)(row0 + rr) * INDIM + kc * 32 + kk];
    }
#pragma unroll
    for (int i = 0; i < 8; i++) {
      const int idx = t + 256 * i;
      const int rr = idx >> 3, kk = (idx & 7) << 2;
      *(float4*)&Ws[rr][kk] = *(const float4*)&Wp[(size_t)rr * INDIM + kc * 32 + kk];
    }
    __syncthreads();
#pragma unroll
    for (int kq = 0; kq < 8; kq++) {
      const float4 xv = *(const float4*)&xs[r][kq * 4];
#pragma unroll
      for (int j = 0; j < 16; j++) {
        const float4 wv = *(const float4*)&Ws[cg + 16 * j][kq * 4];
        acc[j] = fmaf(xv.x, wv.x, fmaf(xv.y, wv.y, fmaf(xv.z, wv.z, fmaf(xv.w, wv.w, acc[j]))));
      }
    }
  }
  __syncthreads();
#pragma unroll
  for (int j = 0; j < 16; j++) {
    const int c = cg + 16 * j;
    const float sg = 1.f / (1.f + expf(-acc[j]));
    float sn, cs;
    __sincosf(TWO_PI_F * sg, &sn, &cs);
    const int hb = __brev((unsigned)c) >> 24;
    sre[r][hb] = cs; sim_[r][hb] = sn;
  }
  __syncthreads();
  const int t16 = t & 15;
  for (int s = 0; s < 8; s++) {
    const int half = 1 << s;
#pragma unroll
    for (int p = 0; p < 8; p++) {
      const int bi = t16 + 16 * p;
      const int jj = bi & (half - 1);
      const int base = (bi >> s) << (s + 1);
      const int i0 = base + jj, i1 = i0 + half;
      const int tw = jj << (7 - s);
      const float wr = twc[tw], wi = -tws[tw];
      const float ar = sre[r][i0], ai = sim_[r][i0];
      const float br = sre[r][i1], b2 = sim_[r][i1];
      const float tr = wr * br - wi * b2, ti = wr * b2 + wi * br;
      sre[r][i0] = ar + tr; sim_[r][i0] = ai + ti;
      sre[r][i1] = ar - tr; sim_[r][i1] = ai - ti;
    }
    __syncthreads();
  }
#pragma unroll
  for (int p = 0; p < 16; p++) {
    const int h = t16 + 16 * p;
    float sn, cs;
    __sincosf(ek[h], &sn, &cs);
    const float xr = sre[r][h], xi = sim_[r][h];
    const size_t o = (size_t)(row0 + r) * HN + h;
    kf_re[o] = xr * cs - xi * sn;
    kf_im[o] = xr * sn + xi * cs;
  }
}

// ---------------------------------------------------------------------------
// K5: Hmix gather + conj(Kf)*Hmix ; IFFT-256 ; readout GEMM (512->72)
// ---------------------------------------------------------------------------
__global__ __launch_bounds__(256) void k5_holo(
    const float* __restrict__ holo_re, const float* __restrict__ holo_im,
    const float* __restrict__ kf_re, const float* __restrict__ kf_im,
    const float* __restrict__ w_ws, const int* __restrict__ itop_ws,
    const float* __restrict__ RW, const float* __restrict__ rb,
    float* __restrict__ triplet)
{
  __shared__ float wsm[16][KSEL];
  __shared__ int   ism[16][KSEL];
  __shared__ float sre[16][260];
  __shared__ float sim_[16][260];
  __shared__ float twc[HN], tws[HN];
  const int t = threadIdx.x;
  const int row0 = blockIdx.x * 16;
  {
    const float a = (float)t * (TWO_PI_F / 256.f);
    twc[t] = cosf(a); tws[t] = sinf(a);
  }
  for (int idx = t; idx < 16 * KSEL; idx += 256) {
    wsm[idx >> 5][idx & 31] = w_ws[(size_t)row0 * KSEL + idx];
    ism[idx >> 5][idx & 31] = itop_ws[(size_t)row0 * KSEL + idx];
  }
  __syncthreads();
  {
    const int h = t;
    const int hb = __brev((unsigned)h) >> 24;
    for (int r = 0; r < 16; r++) {
      float hr = 0.f, hi = 0.f;
#pragma unroll 8
      for (int k2 = 0; k2 < KSEL; k2++) {
        const int m = ism[r][k2];
        const float wk = wsm[r][k2];
        hr = fmaf(wk, holo_re[(size_t)m * HN + h], hr);
        hi = fmaf(wk, holo_im[(size_t)m * HN + h], hi);
      }
      const size_t o = (size_t)(row0 + r) * HN + h;
      const float kr = kf_re[o], ki = kf_im[o];
      sre[r][hb] = kr * hr + ki * hi;
      sim_[r][hb] = kr * hi - ki * hr;
    }
  }
  __syncthreads();
  const int r = t >> 4, t16 = t & 15;
  for (int s = 0; s < 8; s++) {
    const int half = 1 << s;
#pragma unroll
    for (int p = 0; p < 8; p++) {
      const int bi = t16 + 16 * p;
      const int jj = bi & (half - 1);
      const int base = (bi >> s) << (s + 1);
      const int i0 = base + jj, i1 = i0 + half;
      const int tw = jj << (7 - s);
      const float wr = twc[tw], wi = tws[tw];
      const float ar = sre[r][i0], ai = sim_[r][i0];
      const float br = sre[r][i1], b2 = sim_[r][i1];
      const float tr = wr * br - wi * b2, ti = wr * b2 + wi * br;
      sre[r][i0] = ar + tr; sim_[r][i0] = ai + ti;
      sre[r][i1] = ar - tr; sim_[r][i1] = ai - ti;
    }
    __syncthreads();
  }
  float dac[5] = {0.f, 0.f, 0.f, 0.f, 0.f};
  for (int h4 = 0; h4 < 256; h4 += 4) {
    const float4 vr = *(const float4*)&sre[r][h4];
#pragma unroll
    for (int u = 0; u < 5; u++) {
      const int o = t16 + 16 * u;
      if (o < TD) {
        const float4 wv = *(const float4*)&RW[(size_t)o * 512 + h4];
        dac[u] = fmaf(vr.x, wv.x, fmaf(vr.y, wv.y, fmaf(vr.z, wv.z, fmaf(vr.w, wv.w, dac[u]))));
      }
    }
  }
  for (int h4 = 0; h4 < 256; h4 += 4) {
    const float4 vi = *(const float4*)&sim_[r][h4];
#pragma unroll
    for (int u = 0; u < 5; u++) {
      const int o = t16 + 16 * u;
      if (o < TD) {
        const float4 wv = *(const float4*)&RW[(size_t)o * 512 + 256 + h4];
        dac[u] = fmaf(vi.x, wv.x, fmaf(vi.y, wv.y, fmaf(vi.z, wv.z, fmaf(vi.w, wv.w, dac[u]))));
      }
    }
  }
#pragma unroll
  for (int u = 0; u < 5; u++) {
    const int o = t16 + 16 * u;
    if (o < TD) triplet[(size_t)(row0 + r) * TD + o] = rb[o] + dac[u] * (1.f / 256.f);
  }
}

// ---------------------------------------------------------------------------
// K6: out = gelu(LN(triplet@W_out.T + b_out)) * gain
// ---------------------------------------------------------------------------
__global__ __launch_bounds__(256) void k6_out(
    const float* __restrict__ triplet, const float* __restrict__ Wo,
    const float* __restrict__ bo, const float* __restrict__ go,
    const float* __restrict__ bbo, const float* __restrict__ gain,
    float* __restrict__ out)
{
  __shared__ float ts[16][76];
  __shared__ float ys[16][772];
  const int t = threadIdx.x;
  const int row0 = blockIdx.x * 16;
  for (int idx = t; idx < 16 * TD; idx += 256) ts[idx / TD][idx % TD] = triplet[(size_t)row0 * TD + idx];
  __syncthreads();
  float acc[16][3];
#pragma unroll
  for (int rr = 0; rr < 16; rr++) { acc[rr][0] = 0.f; acc[rr][1] = 0.f; acc[rr][2] = 0.f; }
  for (int e = 0; e < TD; e++) {
    float wv[3];
#pragma unroll
    for (int j = 0; j < 3; j++) wv[j] = Wo[(size_t)(t + 256 * j) * TD + e];
#pragma unroll
    for (int rr = 0; rr < 16; rr++) {
      const float tv = ts[rr][e];
      acc[rr][0] = fmaf(tv, wv[0], acc[rr][0]);
      acc[rr][1] = fmaf(tv, wv[1], acc[rr][1]);
      acc[rr][2] = fmaf(tv, wv[2], acc[rr][2]);
    }
  }
  {
    const float b0 = bo[t], b1 = bo[t + 256], b2 = bo[t + 512];
#pragma unroll
    for (int rr = 0; rr < 16; rr++) {
      ys[rr][t] = acc[rr][0] + b0;
      ys[rr][t + 256] = acc[rr][1] + b1;
      ys[rr][t + 512] = acc[rr][2] + b2;
    }
  }
  __syncthreads();
  const int r = t >> 4, kt = t & 15;
  float s = 0.f, sq = 0.f;
  for (int u = 0; u < 48; u++) {
    const float v = ys[r][kt + 16 * u];
    s += v; sq = fmaf(v, v, sq);
  }
#pragma unroll
  for (int m = 1; m < 16; m <<= 1) { s += __shfl_xor(s, m, 16); sq += __shfl_xor(sq, m, 16); }
  const float mean = s * (1.f / 768.f);
  const float var  = sq * (1.f / 768.f) - mean * mean;
  const float rstd = rsqrtf(var + 1e-5f);
  const float gn = gain[row0 + r];
  for (int u = 0; u < 48; u++) {
    const int e = kt + 16 * u;
    const float v = (ys[r][e] - mean) * rstd * go[e] + bbo[e];
    out[(size_t)(row0 + r) * INDIM + e] = gelu_exact(v) * gn;
  }
}

// ---------------------------------------------------------------------------
extern "C" void kernel_launch(void* const* d_in, const int* in_sizes, int n_in,
                              void* d_out, int out_size, void* d_ws, size_t ws_size,
                              hipStream_t stream)
{
  (void)in_sizes; (void)n_in; (void)out_size; (void)ws_size;
  const float* x     = (const float*)d_in[0];
  const float* Wi    = (const float*)d_in[1];
  const float* bi    = (const float*)d_in[2];
  const float* gi    = (const float*)d_in[3];
  const float* bbi   = (const float*)d_in[4];
  const float* ricci = (const float*)d_in[5];
  const float* fw    = (const float*)d_in[6];
  const float* keys  = (const float*)d_in[7];
  const float* Wp    = (const float*)d_in[8];
  const float* bp    = (const float*)d_in[9];
  const float* ek    = (const float*)d_in[10];
  const float* hre   = (const float*)d_in[11];
  const float* him   = (const float*)d_in[12];
  const float* RW    = (const float*)d_in[13];
  const float* rb    = (const float*)d_in[14];
  const float* Wo    = (const float*)d_in[15];
  const float* bo    = (const float*)d_in[16];
  const float* go    = (const float*)d_in[17];
  const float* bbo   = (const float*)d_in[18];
  const float* qp    = (const float*)d_in[19];
  float* out = (float*)d_out;

  char* ws = (char*)d_ws;
  float* qvec    = (float*)(ws + 0);
  float* qnorm   = (float*)(ws + 786432);
  float* kn      = (float*)(ws + 819200);
  float* pm      = (float*)(ws + 851968);
  float* gain    = (float*)(ws + 884736);
  float* w_ws    = (float*)(ws + 917504);
  int*   itop    = (int*)  (ws + 1966080);
  float* triplet = (float*)(ws + 3014656);
  float* kf_re   = (float*)(ws + 5373952);
  float* kf_im   = (float*)(ws + 13762560);

  k1_encode<<<dim3(NROWS / 16), dim3(256), 0, stream>>>(x, Wi, bi, gi, bbi, ricci, qvec, qnorm);
  k2_prep<<<dim3(MKEYS / 256), dim3(256), 0, stream>>>(keys, qp, kn, pm);
  k4_phase<<<dim3(NROWS / 16), dim3(256), 0, stream>>>(x, Wp, bp, ek, kf_re, kf_im);
  k3_topk<<<dim3(NROWS / 32), dim3(256), 0, stream>>>(qvec, qnorm, keys, kn, fw, pm, w_ws, itop, gain);
  k5_holo<<<dim3(NROWS / 16), dim3(256), 0, stream>>>(hre, him, kf_re, kf_im, w_ws, itop, RW, rb, triplet);
  k6_out<<<dim3(NROWS / 16), dim3(256), 0, stream>>>(triplet, Wo, bo, go, bbo, gain, out);
}